// Round 1
// baseline (199.727 us; speedup 1.0000x reference)
//
#include <hip/hip_runtime.h>
#include <cstdint>
#include <cstddef>

#define SEQ 3072
#define DIM 1280
#define NH 16
#define HD 80
#define NQT (SEQ/16)

typedef __attribute__((ext_vector_type(8))) short s16x8;   // 8 x bf16 fragment (4 VGPR)
typedef __attribute__((ext_vector_type(4))) float f32x4;   // MFMA accumulator
typedef unsigned short u16;
typedef unsigned int u32;
typedef unsigned long long u64;

__device__ __forceinline__ u16 f2bf(float f) {
  u32 u = __builtin_bit_cast(u32, f);
  u32 r = (u + 0x7FFFu + ((u >> 16) & 1u)) >> 16;   // round-to-nearest-even
  return (u16)r;
}
__device__ __forceinline__ float bf2f(u16 b) {
  u32 u = ((u32)b) << 16;
  return __builtin_bit_cast(float, u);
}

// ---------------- f32 -> bf16 convert ----------------
__global__ void cvt_kernel(const float* __restrict__ s, u16* __restrict__ d, int n4) {
  int i = blockIdx.x * blockDim.x + threadIdx.x;
  if (i >= n4) return;
  float4 v = ((const float4*)s)[i];
  ushort4 o;
  o.x = f2bf(v.x); o.y = f2bf(v.y); o.z = f2bf(v.z); o.w = f2bf(v.w);
  ((ushort4*)d)[i] = o;
}

// ---------------- bf16 MFMA GEMM: out[m][n] = sum_k A[m][k]*B[n][k] (+bias) ----
// MODE 0: qkv — scatter q,k to [h][s][80], v transposed to [h][80][s] (bf16)
// MODE 1: proj — f32 out [M][N]
template<int MODE>
__global__ __launch_bounds__(256)
void gemm_kernel(const u16* __restrict__ A, const u16* __restrict__ B,
                 const float* __restrict__ bias,
                 u16* __restrict__ qws, u16* __restrict__ kws, u16* __restrict__ vT,
                 float* __restrict__ fout,
                 int M, int N, int K)
{
  constexpr int BM = 128, BN = 128, BK = 32;
  __shared__ u16 As[BM*BK];
  __shared__ u16 Bs[BN*BK];
  const int m0 = blockIdx.y * BM, n0 = blockIdx.x * BN;
  const int tid = threadIdx.x;
  const int lane = tid & 63, wave = tid >> 6;
  const int wr = wave >> 1, wc = wave & 1;     // 2x2 waves, each 64x64
  const int lr = lane & 15, lg = lane >> 4;

  f32x4 acc[4][4];
  #pragma unroll
  for (int i = 0; i < 4; ++i)
    #pragma unroll
    for (int j = 0; j < 4; ++j) acc[i][j] = (f32x4)0.0f;

  for (int k0 = 0; k0 < K; k0 += BK) {
    s16x8 va[2], vb[2];
    #pragma unroll
    for (int i = 0; i < 2; ++i) {
      int c = i*256 + tid;            // 16B chunk id over the 128x32 tile
      int r = c >> 2, cc = c & 3;
      va[i] = *(const s16x8*)(A + (size_t)(m0 + r)*K + k0 + cc*8);
      vb[i] = *(const s16x8*)(B + (size_t)(n0 + r)*K + k0 + cc*8);
    }
    __syncthreads();                  // protect prev iteration's LDS reads
    #pragma unroll
    for (int i = 0; i < 2; ++i) {
      int c = i*256 + tid;
      int r = c >> 2, cc = c & 3;
      *(s16x8*)&As[r*BK + cc*8] = va[i];
      *(s16x8*)&Bs[r*BK + cc*8] = vb[i];
    }
    __syncthreads();
    s16x8 af[4], bf[4];
    #pragma unroll
    for (int i = 0; i < 4; ++i) {
      af[i] = *(const s16x8*)&As[(wr*64 + i*16 + lr)*BK + lg*8];
      bf[i] = *(const s16x8*)&Bs[(wc*64 + i*16 + lr)*BK + lg*8];
    }
    #pragma unroll
    for (int mi = 0; mi < 4; ++mi)
      #pragma unroll
      for (int ni = 0; ni < 4; ++ni)
        acc[mi][ni] = __builtin_amdgcn_mfma_f32_16x16x32_bf16(af[mi], bf[ni], acc[mi][ni], 0, 0, 0);
  }

  // epilogue: D layout col = lane&15, row = (lane>>4)*4 + reg (m89/m91-verified)
  #pragma unroll
  for (int ni = 0; ni < 4; ++ni) {
    const int n = n0 + wc*64 + ni*16 + lr;
    const float bv = bias[n];
    if constexpr (MODE == 0) {
      const int which = n / DIM;
      const int hd = n - which*DIM;
      const int h = hd / HD;
      const int d = hd - h*HD;
      #pragma unroll
      for (int mi = 0; mi < 4; ++mi) {
        const int mb = m0 + wr*64 + mi*16 + lg*4;
        #pragma unroll
        for (int j = 0; j < 4; ++j) {
          const u16 b = f2bf(acc[mi][ni][j] + bv);
          const int m = mb + j;
          if (which == 0)      qws[((size_t)h*SEQ + m)*HD + d] = b;
          else if (which == 1) kws[((size_t)h*SEQ + m)*HD + d] = b;
          else                 vT [((size_t)h*HD + d)*SEQ + m] = b;
        }
      }
    } else {
      #pragma unroll
      for (int mi = 0; mi < 4; ++mi) {
        const int mb = m0 + wr*64 + mi*16 + lg*4;
        #pragma unroll
        for (int j = 0; j < 4; ++j)
          fout[(size_t)(mb + j)*N + n] = acc[mi][ni][j] + bv;
      }
    }
  }
}

// ---------------- RoPE in place on q,k  ([h][s][80] bf16) ----------------
__global__ void rope_kernel(u16* __restrict__ qws, u16* __restrict__ kws,
                            const float* __restrict__ freqs /*[SEQ][40]*/) {
  int idx = blockIdx.x*blockDim.x + threadIdx.x;
  const int total = NH*SEQ*(HD/2);
  if (idx >= total) return;
  int d = idx % (HD/2);
  int s = (idx / (HD/2)) % SEQ;
  int h = idx / ((HD/2)*SEQ);
  float f = freqs[s*(HD/2) + d];
  float cs = cosf(f), sn = sinf(f);
  size_t base = ((size_t)h*SEQ + s)*HD;
  {
    float x = bf2f(qws[base+d]), y = bf2f(qws[base+d+HD/2]);
    qws[base+d]      = f2bf(x*cs - y*sn);
    qws[base+d+HD/2] = f2bf(y*cs + x*sn);
  }
  {
    float x = bf2f(kws[base+d]), y = bf2f(kws[base+d+HD/2]);
    kws[base+d]      = f2bf(x*cs - y*sn);
    kws[base+d+HD/2] = f2bf(y*cs + x*sn);
  }
}

// ---------------- attention: 1 wave = 16 q rows, online softmax ----------------
// swapped QK^T: mfma(A=K, B=Q) -> lane owns q = lane&15, keys (lane>>4)*4+reg
__global__ __launch_bounds__(64)
void attn_kernel(const u16* __restrict__ qws, const u16* __restrict__ kws,
                 const u16* __restrict__ vT, const int* __restrict__ cu, int ncu,
                 u16* __restrict__ ows /* [SEQ][DIM] bf16 */)
{
  __shared__ u16 P_lds[16*32];   // [q][32 keys], XOR-swizzled 8B chunks
  const int blk = blockIdx.x;
  const int h = blk / NQT;
  const int t = blk % NQT;
  const int lane = threadIdx.x;
  const int lr = lane & 15, lg = lane >> 4;
  const int q0 = t*16;
  const float NEG_INF = -__builtin_inff();

  // per-row segment bounds (dynamic from cu_seqlens) + tile union range
  int rs = cu[0], re = cu[1];
  int ts = cu[0], te = cu[1];
  {
    const int qr = q0 + lr;
    for (int i = 1; i < ncu-1; ++i) {
      int lo = cu[i], hi = cu[i+1];
      if (qr    >= lo) { rs = lo; re = hi; }
      if (q0    >= lo) { ts = lo; }
      if (q0+15 >= lo) { te = hi; }
    }
  }

  const float kscale = 0.11180339887498949f * 1.44269504088896341f; // scale*log2(e)

  // Q fragments (B operand): lane holds Q[q0+lr][s*32 + lg*8 .. +7]; pad d>=80 with 0
  s16x8 qf[3];
  #pragma unroll
  for (int s = 0; s < 3; ++s) {
    int d0 = s*32 + lg*8;
    if (d0 < HD) qf[s] = *(const s16x8*)(qws + ((size_t)h*SEQ + q0 + lr)*HD + d0);
    else         qf[s] = (s16x8)(short)0;
  }

  float m_run = NEG_INF;
  float l_run = 0.0f;
  f32x4 oacc[5];
  #pragma unroll
  for (int dt = 0; dt < 5; ++dt) oacc[dt] = (f32x4)0.0f;

  const int swz = (lr >> 1) & 3;

  for (int kc = ts & ~31; kc < te; kc += 32) {
    // QK^T for 2 key sub-tiles of 16
    f32x4 sacc[2];
    #pragma unroll
    for (int kt = 0; kt < 2; ++kt) {
      sacc[kt] = (f32x4)0.0f;
      #pragma unroll
      for (int s = 0; s < 3; ++s) {
        int d0 = s*32 + lg*8;
        s16x8 kf;
        if (d0 < HD) kf = *(const s16x8*)(kws + ((size_t)h*SEQ + kc + kt*16 + lr)*HD + d0);
        else         kf = (s16x8)(short)0;
        sacc[kt] = __builtin_amdgcn_mfma_f32_16x16x32_bf16(kf, qf[s], sacc[kt], 0, 0, 0);
      }
    }
    // lane holds S2[key = kc+kt*16+lg*4+j][q = q0+lr] in log2 domain
    float sv[8];
    float cmax = NEG_INF;
    #pragma unroll
    for (int kt = 0; kt < 2; ++kt)
      #pragma unroll
      for (int j = 0; j < 4; ++j) {
        int key = kc + kt*16 + lg*4 + j;
        float x = sacc[kt][j] * kscale;
        bool valid = (key >= rs) && (key < re);
        x = valid ? x : NEG_INF;
        sv[kt*4+j] = x;
        cmax = fmaxf(cmax, x);
      }
    cmax = fmaxf(cmax, __shfl_xor(cmax, 16, 64));
    cmax = fmaxf(cmax, __shfl_xor(cmax, 32, 64));
    float m_new  = fmaxf(m_run, cmax);
    float fscale = (m_run == m_new) ? 1.0f : exp2f(m_run - m_new);
    float psum = 0.0f;
    u16 pb[8];
    #pragma unroll
    for (int i = 0; i < 8; ++i) {
      float p = (sv[i] == NEG_INF) ? 0.0f : exp2f(sv[i] - m_new);
      psum += p;
      pb[i] = f2bf(p);
    }
    psum += __shfl_xor(psum, 16, 64);
    psum += __shfl_xor(psum, 32, 64);
    l_run = l_run * fscale + psum;
    m_run = m_new;

    // P -> LDS [q=lr][32k]; 8B chunk c stored at c ^ (swz<<1)  (2-way, conflict-free)
    __syncthreads();
    u64 w0 = (u64)pb[0] | ((u64)pb[1]<<16) | ((u64)pb[2]<<32) | ((u64)pb[3]<<48);
    u64 w1 = (u64)pb[4] | ((u64)pb[5]<<16) | ((u64)pb[6]<<32) | ((u64)pb[7]<<48);
    u64* P64 = (u64*)P_lds;
    P64[lr*8 + ( lg      ^ (swz<<1))] = w0;   // keys lg*4..+3
    P64[lr*8 + ((4 + lg) ^ (swz<<1))] = w1;   // keys 16+lg*4..+3
    __syncthreads();

    // rescale factors for PV accumulator rows (row = lg*4+j owns q=lg*4+j)
    float fr[4];
    #pragma unroll
    for (int j = 0; j < 4; ++j)
      fr[j] = __builtin_bit_cast(float,
                __builtin_amdgcn_ds_bpermute((lg*4 + j)*4, __builtin_bit_cast(int, fscale)));

    // P A-fragment: lane needs P[q=lr][k = lg*8..+7] -> swizzled 16B chunk (lg^swz)
    s16x8 pa = *(const s16x8*)&P_lds[lr*32 + ((lg ^ swz) * 8)];

    // PV: B fragments straight from pre-transposed V ([h][80][SEQ])
    #pragma unroll
    for (int dt = 0; dt < 5; ++dt) {
      s16x8 vf = *(const s16x8*)(vT + ((size_t)h*HD + dt*16 + lr)*SEQ + kc + lg*8);
      f32x4 o = oacc[dt];
      #pragma unroll
      for (int j = 0; j < 4; ++j) o[j] *= fr[j];
      oacc[dt] = __builtin_amdgcn_mfma_f32_16x16x32_bf16(pa, vf, o, 0, 0, 0);
    }
  }

  // normalize + store: lane holds out[q = q0+lg*4+j][d = dt*16+lr]
  float linv[4];
  #pragma unroll
  for (int j = 0; j < 4; ++j) {
    float lv = __builtin_bit_cast(float,
                 __builtin_amdgcn_ds_bpermute((lg*4 + j)*4, __builtin_bit_cast(int, l_run)));
    linv[j] = 1.0f / lv;
  }
  #pragma unroll
  for (int dt = 0; dt < 5; ++dt)
    #pragma unroll
    for (int j = 0; j < 4; ++j) {
      float v = oacc[dt][j] * linv[j];
      ows[(size_t)(q0 + lg*4 + j)*DIM + h*HD + dt*16 + lr] = f2bf(v);
    }
}

// ---------------- launch ----------------
extern "C" void kernel_launch(void* const* d_in, const int* in_sizes, int n_in,
                              void* d_out, int out_size, void* d_ws, size_t ws_size,
                              hipStream_t stream) {
  const float* hidden = (const float*)d_in[0];
  const float* rope   = (const float*)d_in[1];
  const int*   cu     = (const int*)d_in[2];
  const float* qkv_w  = (const float*)d_in[3];
  const float* qkv_b  = (const float*)d_in[4];
  const float* proj_w = (const float*)d_in[5];
  const float* proj_b = (const float*)d_in[6];
  float* out = (float*)d_out;
  const int ncu = in_sizes[2];

  // workspace layout (~52.4 MB total)
  char* ws = (char*)d_ws;
  u16* Abf = (u16*)ws; ws += (size_t)SEQ*DIM*2;       // hidden bf16
  u16* Wq  = (u16*)ws; ws += (size_t)3*DIM*DIM*2;     // qkv_w bf16
  u16* Wp  = (u16*)ws; ws += (size_t)DIM*DIM*2;       // proj_w bf16
  u16* qws = (u16*)ws; ws += (size_t)NH*SEQ*HD*2;     // q [h][s][80]
  u16* kws = (u16*)ws; ws += (size_t)NH*SEQ*HD*2;     // k [h][s][80]
  u16* vTw = (u16*)ws; ws += (size_t)NH*SEQ*HD*2;     // v^T [h][80][s]
  u16* ows = (u16*)ws; ws += (size_t)SEQ*DIM*2;       // attn out [s][1280]

  cvt_kernel<<<SEQ*DIM/4/256,       256, 0, stream>>>(hidden, Abf, SEQ*DIM/4);
  cvt_kernel<<<3*DIM*DIM/4/256,     256, 0, stream>>>(qkv_w,  Wq,  3*DIM*DIM/4);
  cvt_kernel<<<DIM*DIM/4/256,       256, 0, stream>>>(proj_w, Wp,  DIM*DIM/4);

  gemm_kernel<0><<<dim3(3*DIM/128, SEQ/128), 256, 0, stream>>>(
      Abf, Wq, qkv_b, qws, kws, vTw, nullptr, SEQ, 3*DIM, DIM);

  rope_kernel<<<(NH*SEQ*(HD/2) + 255)/256, 256, 0, stream>>>(qws, kws, rope);

  attn_kernel<<<NH*NQT, 64, 0, stream>>>(qws, kws, vTw, cu, ncu, ows);

  gemm_kernel<1><<<dim3(DIM/128, SEQ/128), 256, 0, stream>>>(
      ows, Wp, proj_b, nullptr, nullptr, nullptr, out, SEQ, DIM, DIM);
}

// Round 2
// 186.903 us; speedup vs baseline: 1.0686x; 1.0686x over previous
//
#include <hip/hip_runtime.h>
#include <cstdint>
#include <cstddef>

#define SEQ 3072
#define DIM 1280
#define NH 16
#define HD 80

typedef __attribute__((ext_vector_type(8))) short s16x8;   // 8 x bf16 (4 VGPR)
typedef __attribute__((ext_vector_type(4))) float f32x4;   // MFMA accumulator
typedef unsigned short u16;
typedef unsigned int u32;
typedef unsigned long long u64;

__device__ __forceinline__ u16 f2bf(float f) {
  u32 u = __builtin_bit_cast(u32, f);
  u32 r = (u + 0x7FFFu + ((u >> 16) & 1u)) >> 16;   // RNE
  return (u16)r;
}
__device__ __forceinline__ float bf2f(u16 b) {
  u32 u = ((u32)b) << 16;
  return __builtin_bit_cast(float, u);
}
__device__ __forceinline__ u32 cvtpk_bf16(float lo, float hi) {
  u32 r;
  asm("v_cvt_pk_bf16_f32 %0, %1, %2" : "=v"(r) : "v"(lo), "v"(hi));
  return r;
}
__device__ __forceinline__ void gload16(const u16* g, u16* lds) {
  __builtin_amdgcn_global_load_lds((const __attribute__((address_space(1))) void*)g,
                                   (__attribute__((address_space(3))) void*)lds,
                                   16, 0, 0);
}

// ---------------- f32 -> bf16 convert ----------------
__global__ void cvt_kernel(const float* __restrict__ s, u16* __restrict__ d, int n4) {
  int i = blockIdx.x * blockDim.x + threadIdx.x;
  if (i >= n4) return;
  float4 v = ((const float4*)s)[i];
  ushort4 o;
  o.x = f2bf(v.x); o.y = f2bf(v.y); o.z = f2bf(v.z); o.w = f2bf(v.w);
  ((ushort4*)d)[i] = o;
}

// ---------------- bf16 MFMA GEMM (global_load_lds staging, m97 structure) ----
// MODE 0: qkv — scatter q,k to [h][s][80], v transposed to [h][80][s] (bf16)
// MODE 1: proj — f32 out [M][N]
template<int MODE>
__global__ __launch_bounds__(256)
void gemm_kernel(const u16* __restrict__ A, const u16* __restrict__ B,
                 const float* __restrict__ bias,
                 u16* __restrict__ qws, u16* __restrict__ kws, u16* __restrict__ vT,
                 float* __restrict__ fout,
                 int M, int N, int K)
{
  constexpr int BM = 128, BN = 128, BK = 32;
  __shared__ __align__(16) u16 As[BM*BK];
  __shared__ __align__(16) u16 Bs[BN*BK];
  const int m0 = blockIdx.y * BM, n0 = blockIdx.x * BN;
  const int tid = threadIdx.x;
  const int lane = tid & 63, wave = tid >> 6;
  const int wr = wave >> 1, wc = wave & 1;     // 2x2 waves, each 64x64
  const int lr = lane & 15, lg = lane >> 4;

  f32x4 acc[4][4];
  #pragma unroll
  for (int i = 0; i < 4; ++i)
    #pragma unroll
    for (int j = 0; j < 4; ++j) acc[i][j] = (f32x4)0.0f;

  for (int k0 = 0; k0 < K; k0 += BK) {
    __syncthreads();                  // prev iteration's LDS reads done
    #pragma unroll
    for (int i = 0; i < 2; ++i) {
      const int c = i*256 + tid;      // 16B chunk id over the 128x32 tile
      const int r = c >> 2, cc = c & 3;
      const int wb = i*256 + (tid & ~63);   // wave-uniform chunk base
      gload16(A + (size_t)(m0 + r)*K + k0 + cc*8, As + wb*8);
      gload16(B + (size_t)(n0 + r)*K + k0 + cc*8, Bs + wb*8);
    }
    __syncthreads();                  // drains vmcnt: tiles landed
    s16x8 af[4], bf[4];
    #pragma unroll
    for (int i = 0; i < 4; ++i) {
      af[i] = *(const s16x8*)&As[(wr*64 + i*16 + lr)*BK + lg*8];
      bf[i] = *(const s16x8*)&Bs[(wc*64 + i*16 + lr)*BK + lg*8];
    }
    #pragma unroll
    for (int mi = 0; mi < 4; ++mi)
      #pragma unroll
      for (int ni = 0; ni < 4; ++ni)
        acc[mi][ni] = __builtin_amdgcn_mfma_f32_16x16x32_bf16(af[mi], bf[ni], acc[mi][ni], 0, 0, 0);
  }

  // epilogue: D layout col = lane&15, row = (lane>>4)*4 + reg
  #pragma unroll
  for (int ni = 0; ni < 4; ++ni) {
    const int n = n0 + wc*64 + ni*16 + lr;
    const float bv = bias[n];
    if constexpr (MODE == 0) {
      const int which = n / DIM;
      const int hd = n - which*DIM;
      const int h = hd / HD;
      const int d = hd - h*HD;
      #pragma unroll
      for (int mi = 0; mi < 4; ++mi) {
        const int mb = m0 + wr*64 + mi*16 + lg*4;
        #pragma unroll
        for (int j = 0; j < 4; ++j) {
          const u16 b = f2bf(acc[mi][ni][j] + bv);
          const int m = mb + j;
          if (which == 0)      qws[((size_t)h*SEQ + m)*HD + d] = b;
          else if (which == 1) kws[((size_t)h*SEQ + m)*HD + d] = b;
          else                 vT [((size_t)h*HD + d)*SEQ + m] = b;
        }
      }
    } else {
      #pragma unroll
      for (int mi = 0; mi < 4; ++mi) {
        const int mb = m0 + wr*64 + mi*16 + lg*4;
        #pragma unroll
        for (int j = 0; j < 4; ++j)
          fout[(size_t)(mb + j)*N + n] = acc[mi][ni][j] + bv;
      }
    }
  }
}

// ---------------- RoPE: cos/sin table, then vectorized apply ----------------
__global__ void rope_tab_kernel(const float* __restrict__ freqs, float2* __restrict__ tab, int n) {
  int i = blockIdx.x*blockDim.x + threadIdx.x;
  if (i >= n) return;
  float f = freqs[i];
  tab[i] = make_float2(cosf(f), sinf(f));
}

__global__ void rope_apply_kernel(u16* __restrict__ q, u16* __restrict__ k,
                                  const float2* __restrict__ tab) {
  int idx = blockIdx.x*blockDim.x + threadIdx.x;   // NH*SEQ*5
  if (idx >= NH*SEQ*5) return;
  const int c = idx % 5;
  const int s = (idx / 5) % SEQ;
  const int h = idx / (5*SEQ);
  const int d0 = c*8;
  const float2* tp = tab + s*(HD/2) + d0;
  float cs[8], sn[8];
  #pragma unroll
  for (int j = 0; j < 8; ++j) { float2 f = tp[j]; cs[j] = f.x; sn[j] = f.y; }
  const size_t base = ((size_t)h*SEQ + s)*HD;
  {
    s16x8 x = *(const s16x8*)(q + base + d0);
    s16x8 y = *(const s16x8*)(q + base + (HD/2) + d0);
    s16x8 nx, ny;
    #pragma unroll
    for (int j = 0; j < 8; ++j) {
      float xv = bf2f((u16)x[j]), yv = bf2f((u16)y[j]);
      nx[j] = (short)f2bf(xv*cs[j] - yv*sn[j]);
      ny[j] = (short)f2bf(yv*cs[j] + xv*sn[j]);
    }
    *(s16x8*)(q + base + d0) = nx;
    *(s16x8*)(q + base + (HD/2) + d0) = ny;
  }
  {
    s16x8 x = *(const s16x8*)(k + base + d0);
    s16x8 y = *(const s16x8*)(k + base + (HD/2) + d0);
    s16x8 nx, ny;
    #pragma unroll
    for (int j = 0; j < 8; ++j) {
      float xv = bf2f((u16)x[j]), yv = bf2f((u16)y[j]);
      nx[j] = (short)f2bf(xv*cs[j] - yv*sn[j]);
      ny[j] = (short)f2bf(yv*cs[j] + xv*sn[j]);
    }
    *(s16x8*)(k + base + d0) = nx;
    *(s16x8*)(k + base + (HD/2) + d0) = ny;
  }
}

// ---------------- attention: 1 wave = 32 q rows, online softmax, no barriers ----
// swapped QK^T: mfma(A=K, B=Q_qs) -> lane owns q = q0+qs*16+(lane&15),
// keys kc + kt*16 + (lane>>4)*4 + j. log2-domain softmax with defer-max (THR=8).
__global__ __launch_bounds__(64)
void attn_kernel(const u16* __restrict__ qws, const u16* __restrict__ kws,
                 const u16* __restrict__ vT, const int* __restrict__ cu, int ncu,
                 u16* __restrict__ ows /* [SEQ][DIM] bf16 */)
{
  __shared__ __align__(16) u16 P_lds[2][16][32];  // per-qset [q][32 keys], swizzled 8B chunks
  const int h = blockIdx.x / (SEQ/32);
  const int t = blockIdx.x % (SEQ/32);
  const int lane = threadIdx.x;
  const int lr = lane & 15, lg = lane >> 4;
  const int q0 = t*32;
  const float NEG = -__builtin_inff();
  const float DTH = 8.0f;   // defer-max threshold (log2 domain): P <= 2^8

  // per-row segment bounds (qset0 row = q0+lr, qset1 row = q0+16+lr) + tile union
  int rs0 = cu[0], re0 = cu[1], rs1 = cu[0], re1 = cu[1];
  int ts = cu[0], te = cu[1];
  {
    const int qa = q0 + lr, qb = q0 + 16 + lr;
    for (int i = 1; i < ncu-1; ++i) {
      int lo = cu[i], hi = cu[i+1];
      if (qa    >= lo) { rs0 = lo; re0 = hi; }
      if (qb    >= lo) { rs1 = lo; re1 = hi; }
      if (q0    >= lo) { ts = lo; }
      if (q0+31 >= lo) { te = hi; }
    }
  }

  const float kscale = 0.11180339887498949f * 1.44269504088896341f; // 1/sqrt(80)*log2(e)

  // Q fragments (B operand), 2 qsets; pad d>=80 with 0
  s16x8 qf[2][3];
  #pragma unroll
  for (int qs = 0; qs < 2; ++qs)
    #pragma unroll
    for (int s = 0; s < 3; ++s) {
      int d0 = s*32 + lg*8;
      if (d0 < HD) qf[qs][s] = *(const s16x8*)(qws + ((size_t)h*SEQ + q0 + qs*16 + lr)*HD + d0);
      else         qf[qs][s] = (s16x8)(short)0;
    }

  float m_run[2] = {NEG, NEG};
  float l_run[2] = {0.0f, 0.0f};
  f32x4 oacc[2][5];
  #pragma unroll
  for (int qs = 0; qs < 2; ++qs)
    #pragma unroll
    for (int dt = 0; dt < 5; ++dt) oacc[qs][dt] = (f32x4)0.0f;

  const int swz = (lr >> 1) & 3;

  for (int kc = ts & ~31; kc < te; kc += 32) {
    // ---- QK^T: K fragments shared by both qsets ----
    f32x4 sacc[2][2];
    #pragma unroll
    for (int qs = 0; qs < 2; ++qs)
      #pragma unroll
      for (int kt = 0; kt < 2; ++kt) sacc[qs][kt] = (f32x4)0.0f;
    #pragma unroll
    for (int kt = 0; kt < 2; ++kt)
      #pragma unroll
      for (int s = 0; s < 3; ++s) {
        int d0 = s*32 + lg*8;
        s16x8 kf;
        if (d0 < HD) kf = *(const s16x8*)(kws + ((size_t)h*SEQ + kc + kt*16 + lr)*HD + d0);
        else         kf = (s16x8)(short)0;
        sacc[0][kt] = __builtin_amdgcn_mfma_f32_16x16x32_bf16(kf, qf[0][s], sacc[0][kt], 0, 0, 0);
        sacc[1][kt] = __builtin_amdgcn_mfma_f32_16x16x32_bf16(kf, qf[1][s], sacc[1][kt], 0, 0, 0);
      }

    // ---- scores (log2 domain) + optional masking ----
    float sv[2][8];
    #pragma unroll
    for (int qs = 0; qs < 2; ++qs)
      #pragma unroll
      for (int kt = 0; kt < 2; ++kt)
        #pragma unroll
        for (int j = 0; j < 4; ++j)
          sv[qs][kt*4+j] = sacc[qs][kt][j] * kscale;

    const bool full = __all((kc >= rs0) && (kc+32 <= re0) && (kc >= rs1) && (kc+32 <= re1));
    if (!full) {
      #pragma unroll
      for (int qs = 0; qs < 2; ++qs) {
        const int rsq = qs ? rs1 : rs0, req = qs ? re1 : re0;
        #pragma unroll
        for (int kt = 0; kt < 2; ++kt)
          #pragma unroll
          for (int j = 0; j < 4; ++j) {
            const int key = kc + kt*16 + lg*4 + j;
            if (key < rsq || key >= req) sv[qs][kt*4+j] = NEG;
          }
      }
    }

    // ---- row max (4-lane-group reduce over key groups) ----
    float cmax[2];
    #pragma unroll
    for (int qs = 0; qs < 2; ++qs) {
      float c = sv[qs][0];
      #pragma unroll
      for (int i = 1; i < 8; ++i) c = fmaxf(c, sv[qs][i]);
      c = fmaxf(c, __shfl_xor(c, 16, 64));
      c = fmaxf(c, __shfl_xor(c, 32, 64));
      cmax[qs] = c;
    }

    // ---- defer-max: rescale only when max grew past THR (NaN-safe) ----
    const bool nore = __all((cmax[0] - m_run[0] <= DTH) && (cmax[1] - m_run[1] <= DTH));
    float psum[2];
    u32 pk[2][4];
    if (nore) {
      #pragma unroll
      for (int qs = 0; qs < 2; ++qs) {
        const float m = m_run[qs];
        float ps = 0.0f;
        #pragma unroll
        for (int i2 = 0; i2 < 4; ++i2) {
          float pa = __builtin_amdgcn_exp2f(sv[qs][2*i2]   - m);
          float pb = __builtin_amdgcn_exp2f(sv[qs][2*i2+1] - m);
          ps += pa + pb;
          pk[qs][i2] = cvtpk_bf16(pa, pb);
        }
        psum[qs] = ps;
      }
    } else {
      #pragma unroll
      for (int qs = 0; qs < 2; ++qs) {
        const float mn = fmaxf(m_run[qs], cmax[qs]);
        const float fs = (mn == m_run[qs]) ? 1.0f : __builtin_amdgcn_exp2f(m_run[qs] - mn);
        float ps = 0.0f;
        #pragma unroll
        for (int i2 = 0; i2 < 4; ++i2) {
          float a0 = sv[qs][2*i2], a1 = sv[qs][2*i2+1];
          float pa = (a0 == NEG) ? 0.0f : __builtin_amdgcn_exp2f(a0 - mn);
          float pb = (a1 == NEG) ? 0.0f : __builtin_amdgcn_exp2f(a1 - mn);
          ps += pa + pb;
          pk[qs][i2] = cvtpk_bf16(pa, pb);
        }
        psum[qs] = ps;
        l_run[qs] *= fs;
        m_run[qs] = mn;
        float fr[4];
        #pragma unroll
        for (int j = 0; j < 4; ++j)
          fr[j] = __builtin_bit_cast(float,
                    __builtin_amdgcn_ds_bpermute((lg*4 + j)*4, __builtin_bit_cast(int, fs)));
        #pragma unroll
        for (int dt = 0; dt < 5; ++dt)
          #pragma unroll
          for (int j = 0; j < 4; ++j) oacc[qs][dt][j] *= fr[j];
      }
    }
    #pragma unroll
    for (int qs = 0; qs < 2; ++qs) {
      float ps = psum[qs];
      ps += __shfl_xor(ps, 16, 64);
      ps += __shfl_xor(ps, 32, 64);
      l_run[qs] += ps;
    }

    // ---- P -> LDS (swizzled 8B chunks; single wave, no barrier needed) ----
    #pragma unroll
    for (int qs = 0; qs < 2; ++qs) {
      u64 w0 = (u64)pk[qs][0] | ((u64)pk[qs][1] << 32);
      u64 w1 = (u64)pk[qs][2] | ((u64)pk[qs][3] << 32);
      u64* P64 = (u64*)&P_lds[qs][0][0];
      P64[lr*8 + ( lg      ^ (swz<<1))] = w0;   // keys lg*4..+3
      P64[lr*8 + ((4 + lg) ^ (swz<<1))] = w1;   // keys 16+lg*4..+3
    }
    s16x8 pa0 = *(const s16x8*)&P_lds[0][lr][(lg ^ swz) * 8];
    s16x8 pa1 = *(const s16x8*)&P_lds[1][lr][(lg ^ swz) * 8];

    // ---- PV: V fragments shared by both qsets ----
    #pragma unroll
    for (int dt = 0; dt < 5; ++dt) {
      s16x8 vf = *(const s16x8*)(vT + ((size_t)h*HD + dt*16 + lr)*SEQ + kc + lg*8);
      oacc[0][dt] = __builtin_amdgcn_mfma_f32_16x16x32_bf16(pa0, vf, oacc[0][dt], 0, 0, 0);
      oacc[1][dt] = __builtin_amdgcn_mfma_f32_16x16x32_bf16(pa1, vf, oacc[1][dt], 0, 0, 0);
    }
  }

  // ---- normalize + store: lane holds out[q = q0+qs*16+lg*4+j][d = dt*16+lr] ----
  #pragma unroll
  for (int qs = 0; qs < 2; ++qs) {
    float linv[4];
    #pragma unroll
    for (int j = 0; j < 4; ++j) {
      float lv = __builtin_bit_cast(float,
                   __builtin_amdgcn_ds_bpermute((lg*4 + j)*4, __builtin_bit_cast(int, l_run[qs])));
      linv[j] = 1.0f / lv;
    }
    #pragma unroll
    for (int dt = 0; dt < 5; ++dt)
      #pragma unroll
      for (int j = 0; j < 4; ++j) {
        float v = oacc[qs][dt][j] * linv[j];
        ows[(size_t)(q0 + qs*16 + lg*4 + j)*DIM + h*HD + dt*16 + lr] = f2bf(v);
      }
  }
}

// ---------------- launch ----------------
extern "C" void kernel_launch(void* const* d_in, const int* in_sizes, int n_in,
                              void* d_out, int out_size, void* d_ws, size_t ws_size,
                              hipStream_t stream) {
  const float* hidden = (const float*)d_in[0];
  const float* rope   = (const float*)d_in[1];
  const int*   cu     = (const int*)d_in[2];
  const float* qkv_w  = (const float*)d_in[3];
  const float* qkv_b  = (const float*)d_in[4];
  const float* proj_w = (const float*)d_in[5];
  const float* proj_b = (const float*)d_in[6];
  float* out = (float*)d_out;
  const int ncu = in_sizes[2];

  // workspace layout (~52.4 MB total)
  char* ws = (char*)d_ws;
  u16* Abf = (u16*)ws; ws += (size_t)SEQ*DIM*2;       // hidden bf16 (reused as rope table after gemm0)
  u16* Wq  = (u16*)ws; ws += (size_t)3*DIM*DIM*2;     // qkv_w bf16
  u16* Wp  = (u16*)ws; ws += (size_t)DIM*DIM*2;       // proj_w bf16
  u16* qws = (u16*)ws; ws += (size_t)NH*SEQ*HD*2;     // q [h][s][80]
  u16* kws = (u16*)ws; ws += (size_t)NH*SEQ*HD*2;     // k [h][s][80]
  u16* vTw = (u16*)ws; ws += (size_t)NH*SEQ*HD*2;     // v^T [h][80][s]
  u16* ows = (u16*)ws; ws += (size_t)SEQ*DIM*2;       // attn out [s][1280]

  cvt_kernel<<<SEQ*DIM/4/256,   256, 0, stream>>>(hidden, Abf, SEQ*DIM/4);
  cvt_kernel<<<3*DIM*DIM/4/256, 256, 0, stream>>>(qkv_w,  Wq,  3*DIM*DIM/4);
  cvt_kernel<<<DIM*DIM/4/256,   256, 0, stream>>>(proj_w, Wp,  DIM*DIM/4);

  gemm_kernel<0><<<dim3(3*DIM/128, SEQ/128), 256, 0, stream>>>(
      Abf, Wq, qkv_b, qws, kws, vTw, nullptr, SEQ, 3*DIM, DIM);

  // rope table overwrites Abf (dead after gemm0)
  float2* tab = (float2*)Abf;
  rope_tab_kernel<<<(SEQ*(HD/2) + 255)/256, 256, 0, stream>>>(rope, tab, SEQ*(HD/2));
  rope_apply_kernel<<<(NH*SEQ*5 + 255)/256, 256, 0, stream>>>(qws, kws, tab);

  attn_kernel<<<NH*(SEQ/32), 64, 0, stream>>>(qws, kws, vTw, cu, ncu, ows);

  gemm_kernel<1><<<dim3(DIM/128, SEQ/128), 256, 0, stream>>>(
      ows, Wp, proj_b, nullptr, nullptr, nullptr, out, SEQ, DIM, DIM);
}